// Round 1
// baseline (134.555 us; speedup 1.0000x reference)
//
#include <hip/hip_runtime.h>

// Problem constants (from reference):
//   B=256, A=128, D=5, FA=256, FB=64, C=256, F = FA+FB = 320
// Key insight: mask = (deg == arange(D)); deg==D (all 5 edges valid, ~96% of
// rows) selects NOTHING -> output row is exactly zero. Only rows with
// deg < 5 need the matvec feat(320) @ W[deg](320x256).

#define NB 256
#define NA 128
#define ND 5
#define NFA 256
#define NFB 64
#define NC 256
#define NF (NFA + NFB)   // 320

__global__ __launch_bounds__(256) void ngh_kernel(
    const float* __restrict__ atoms,   // B*A*FA
    const float* __restrict__ bonds,   // B*A*D*FB
    const int*   __restrict__ edges,   // B*A*D
    const float* __restrict__ W,       // D*F*C
    const float* __restrict__ bias,    // D*C
    float* __restrict__ out)           // B*A*C
{
    const int row = blockIdx.x;        // row = b*A + a
    const int b   = row >> 7;          // / NA
    const int a   = row & (NA - 1);    // % NA
    const int t   = threadIdx.x;       // 0..255 -> output channel

    // Edges for this row: addresses are block-uniform -> scalar loads.
    int e[ND];
    int deg = 0;
#pragma unroll
    for (int d = 0; d < ND; ++d) {
        e[d] = edges[row * ND + d];
        deg += (e[d] != -1) ? 1 : 0;
    }

    float* orow = out + (size_t)row * NC;

    if (deg >= ND) {
        // mask selects nothing -> exact zero output (out is poisoned, must write)
        orow[t] = 0.0f;
        return;
    }

    // Build feat = [summed_atom (256) | summed_bond (64)] in LDS.
    __shared__ float feat[NF];
    {
        // summed_atom[f] = atoms[b,a,f] + sum over valid neighbors
        const float* arow = atoms + ((size_t)b * NA + a) * NFA;
        float v = arow[t];
#pragma unroll
        for (int d = 0; d < ND; ++d) {
            if (e[d] != -1) {
                v += atoms[((size_t)b * NA + e[d]) * NFA + t];
            }
        }
        feat[t] = v;
    }
    if (t < NFB) {
        // summed_bond[f] = sum over ALL d of bonds[b,a,d,f] (no mask in ref)
        const float* brow = bonds + ((size_t)b * NA + a) * (ND * NFB);
        float v = 0.0f;
#pragma unroll
        for (int d = 0; d < ND; ++d) v += brow[d * NFB + t];
        feat[NFA + t] = v;
    }
    __syncthreads();

    // out[c=t] = relu( sum_f feat[f] * W[deg][f][c] + bias[deg][c] )
    // W reads: consecutive threads -> consecutive c -> fully coalesced.
    // feat[f] is a same-address LDS broadcast -> no bank conflicts.
    const float* Wd = W + (size_t)deg * NF * NC + t;
    float acc = bias[deg * NC + t];
#pragma unroll 8
    for (int f = 0; f < NF; ++f) {
        acc = fmaf(feat[f], Wd[(size_t)f * NC], acc);
    }
    orow[t] = fmaxf(acc, 0.0f);
}

extern "C" void kernel_launch(void* const* d_in, const int* in_sizes, int n_in,
                              void* d_out, int out_size, void* d_ws, size_t ws_size,
                              hipStream_t stream) {
    const float* atoms = (const float*)d_in[0];
    const float* bonds = (const float*)d_in[1];
    const int*   edges = (const int*)  d_in[2];
    const float* W     = (const float*)d_in[3];
    const float* bias  = (const float*)d_in[4];
    float*       out   = (float*)d_out;

    dim3 grid(NB * NA);   // one block per (b,a) row = 32768 blocks
    dim3 block(NC);       // 256 threads = one output channel each
    ngh_kernel<<<grid, block, 0, stream>>>(atoms, bonds, edges, W, bias, out);
}